// Round 7
// baseline (51.129 us; speedup 1.0000x reference)
//
#include <hip/hip_runtime.h>
#include <math.h>

#define CCH 256
#define HMD 128
#define HW (HMD*HMD)          // 16384
#define NTOT (8*HW)           // 131072 per channel
#define OH 11
#define OW 8
#define NPIX (OH*OW)          // 88
#define NPAIR 16

// ws float layout:
// [0..1023]       chan sum partial, slot pb = b*256+c (b in [0,4)), covers planes pb and pb+1024
// [1024..2047]    chan sumsq partial
// [2048..18431]   triplet partials: ((pair*256+c)*4) + {S1pd, S2pd, S1nd, S2nd}
// [18432..18687]  focal partials: 128 x {lsum, npos}
// [18688]         ticket (uint), reset to 0 by a 4-byte hipMemsetAsync each call
#define CH_SUM 0
#define CH_SQ  1024
#define TRI    2048
#define FOC    18432
#define CNT    18688

#define NTRIPLET 128
#define NFOCAL   128
#define NPLANE2  1024
#define NBLOCKS  (NTRIPLET + NFOCAL + NPLANE2)   // 1280 = 5 blocks/CU, fully co-resident

// Publish a partial through the coherence point (device-coherent RMW, no fence).
__device__ __forceinline__ void pub(float* p, float v) { atomicExch(p, v); }
// Read a partial through the coherence point (RMW read, bypasses stale L1/L2).
__device__ __forceinline__ float rd(float* p) { return atomicAdd(p, 0.0f); }

__device__ __forceinline__ void block_reduce2_256(float& a, float& b) {
    #pragma unroll
    for (int off = 32; off > 0; off >>= 1) {
        a += __shfl_down(a, off, 64);
        b += __shfl_down(b, off, 64);
    }
    __shared__ float sa[4], sb[4];
    int wid  = threadIdx.x >> 6;
    int lane = threadIdx.x & 63;
    if (lane == 0) { sa[wid] = a; sb[wid] = b; }
    __syncthreads();
    if (threadIdx.x == 0) {
        a = sa[0] + sa[1] + sa[2] + sa[3];
        b = sb[0] + sb[1] + sb[2] + sb[3];
    }
}

// Single kernel. Roles: triplet [0,128), focal [128,256), planes [256,1280).
// Partials published via atomicExch; last-finishing block (ticket) finalizes.
// NO __threadfence anywhere (R4 lesson: agent fence = L2 wb/inv per block).
__global__ void mega(const float* __restrict__ simi,
                     const float* __restrict__ hm,
                     const float* __restrict__ gt,
                     const int* __restrict__ bboxf,
                     const int* __restrict__ bboxm,
                     const float* __restrict__ gamma,
                     float* __restrict__ ws,
                     float* __restrict__ out) {
    const int bid = blockIdx.x;
    const int tid = threadIdx.x;

    if (bid < NTRIPLET) {
        // ---- triplet gather (overlaps the stream) ----
        int pair  = bid >> 3;
        int slice = bid & 7;

        __shared__ int   sYA[3][OH], sYB[3][OH], sXA[3][OW], sXB[3][OW];
        __shared__ float sWY[3][OH], sWX[3][OW];
        __shared__ int   sBase[3];

        if (tid < 3) {
            const int* bx;
            int bidx;
            if (tid == 0)      { bx = bboxf + pair * 4;        bidx = pair >> 2; }       // anchor
            else if (tid == 1) { bx = bboxf + (16 + pair) * 4; bidx = 4 + (pair >> 2); } // positive
            else               { bx = bboxm + pair * 4;        bidx = pair >> 1; }       // negative
            int x0 = bx[0], y0 = bx[1], x1 = bx[2], y1 = bx[3];
            float h = (float)(y1 - y0), w = (float)(x1 - x0);
            for (int j = 0; j < OH; ++j) {
                float sy = fminf(fmaxf((j + 0.5f) * h / (float)OH - 0.5f, 0.0f), h - 1.0f);
                int ylo = (int)floorf(sy);
                sYA[tid][j] = y0 + ylo;
                sYB[tid][j] = y0 + min(ylo + 1, y1 - y0 - 1);
                sWY[tid][j] = sy - (float)ylo;
            }
            for (int j = 0; j < OW; ++j) {
                float sx = fminf(fmaxf((j + 0.5f) * w / (float)OW - 0.5f, 0.0f), w - 1.0f);
                int xlo = (int)floorf(sx);
                sXA[tid][j] = x0 + xlo;
                sXB[tid][j] = x0 + min(xlo + 1, x1 - x0 - 1);
                sWX[tid][j] = sx - (float)xlo;
            }
            sBase[tid] = bidx * CCH * HW;
        }
        __syncthreads();

        int cl = tid >> 3;          // 0..31: channel within slice
        int lx = tid & 7;           // output column
        int c  = slice * 32 + cl;

        const float* imgA = simi + sBase[0] + c * HW;
        const float* imgP = simi + sBase[1] + c * HW;
        const float* imgN = simi + sBase[2] + c * HW;

        float a1p = 0.f, a2p = 0.f, a1n = 0.f, a2n = 0.f;
        float wxA = sWX[0][lx], wxP = sWX[1][lx], wxN = sWX[2][lx];
        int xaA = sXA[0][lx], xbA = sXB[0][lx];
        int xaP = sXA[1][lx], xbP = sXB[1][lx];
        int xaN = sXA[2][lx], xbN = sXB[2][lx];

        #pragma unroll
        for (int y = 0; y < OH; ++y) {
            float wyA = sWY[0][y], wyP = sWY[1][y], wyN = sWY[2][y];
            int yaA = sYA[0][y] * HMD, ybA = sYB[0][y] * HMD;
            int yaP = sYA[1][y] * HMD, ybP = sYB[1][y] * HMD;
            int yaN = sYA[2][y] * HMD, ybN = sYB[2][y] * HMD;

            float vA, vP, vN;
            {
                float v00 = imgA[yaA + xaA], v01 = imgA[yaA + xbA];
                float v10 = imgA[ybA + xaA], v11 = imgA[ybA + xbA];
                float top = (1.0f - wxA) * v00 + wxA * v01;
                float bot = (1.0f - wxA) * v10 + wxA * v11;
                vA = (1.0f - wyA) * top + wyA * bot;
            }
            {
                float v00 = imgP[yaP + xaP], v01 = imgP[yaP + xbP];
                float v10 = imgP[ybP + xaP], v11 = imgP[ybP + xbP];
                float top = (1.0f - wxP) * v00 + wxP * v01;
                float bot = (1.0f - wxP) * v10 + wxP * v11;
                vP = (1.0f - wyP) * top + wyP * bot;
            }
            {
                float v00 = imgN[yaN + xaN], v01 = imgN[yaN + xbN];
                float v10 = imgN[ybN + xaN], v11 = imgN[ybN + xbN];
                float top = (1.0f - wxN) * v00 + wxN * v01;
                float bot = (1.0f - wxN) * v10 + wxN * v11;
                vN = (1.0f - wyN) * top + wyN * bot;
            }
            float dp = vA - vP; a1p += dp; a2p += dp * dp;
            float dn = vA - vN; a1n += dn; a2n += dn * dn;
        }
        #pragma unroll
        for (int off = 4; off > 0; off >>= 1) {
            a1p += __shfl_down(a1p, off, 8);
            a2p += __shfl_down(a2p, off, 8);
            a1n += __shfl_down(a1n, off, 8);
            a2n += __shfl_down(a2n, off, 8);
        }
        if (lx == 0) {
            float* q = ws + TRI + (pair * 256 + c) * 4;
            pub(q + 0, a1p); pub(q + 1, a2p); pub(q + 2, a1n); pub(q + 3, a2n);
        }
    } else if (bid < NTRIPLET + NFOCAL) {
        // ---- focal partial ----
        int fb = bid - NTRIPLET;
        int i = fb * 256 + tid;
        float4 hv = ((const float4*)hm)[i];
        float4 gv = ((const float4*)gt)[i];
        float lsum = 0.f, npos = 0.f;
        #pragma unroll
        for (int j = 0; j < 4; ++j) {
            float x = (&hv.x)[j], g = (&gv.x)[j];
            float pred = 1.0f / (1.0f + expf(-x));
            pred = fminf(fmaxf(pred, 1e-4f), 1.0f - 1e-4f);
            if (g == 1.0f) {
                float om = 1.0f - pred;
                lsum += logf(pred) * om * om;
                npos += 1.0f;
            } else {
                float gg = 1.0f - g;
                float g2 = gg * gg;
                lsum += logf(1.0f - pred) * pred * pred * (g2 * g2);
            }
        }
        block_reduce2_256(lsum, npos);
        if (tid == 0) { pub(ws + FOC + 2 * fb, lsum); pub(ws + FOC + 2 * fb + 1, npos); }
    } else {
        // ---- channel-plane sums: block handles planes pb and pb+1024 (same channel) ----
        int pb = bid - NTRIPLET - NFOCAL;           // 0..1023
        const float4* pa = (const float4*)(simi + (size_t)pb * HW);
        const float4* pc = (const float4*)(simi + (size_t)(pb + 1024) * HW);
        float s = 0.f, s2 = 0.f;
        #pragma unroll
        for (int it = 0; it < 16; ++it) {
            float4 va = pa[it * 256 + tid];
            float4 vb = pc[it * 256 + tid];
            s  += va.x + va.y + va.z + va.w;
            s2 += va.x*va.x + va.y*va.y + va.z*va.z + va.w*va.w;
            s  += vb.x + vb.y + vb.z + vb.w;
            s2 += vb.x*vb.x + vb.y*vb.y + vb.z*vb.z + vb.w*vb.w;
        }
        block_reduce2_256(s, s2);
        if (tid == 0) { pub(ws + CH_SUM + pb, s); pub(ws + CH_SQ + pb, s2); }
    }

    // ---- ticket: __syncthreads drains vmcnt(0) => this block's atomics complete ----
    __shared__ int sLast;
    __syncthreads();
    if (tid == 0) {
        unsigned int old = atomicAdd((unsigned int*)(ws + CNT), 1u);
        sLast = (old == (unsigned int)(NBLOCKS - 1)) ? 1 : 0;
    }
    __syncthreads();
    if (!sLast) return;

    // ---------------- finalize (last-finishing block, 256 threads) ----------------
    __shared__ float s_sh[256], tr[NPAIR];
    int t = tid;

    float su = 0.f, sq = 0.f;
    #pragma unroll
    for (int b = 0; b < 4; ++b) {
        su += rd(ws + CH_SUM + b * 256 + t);
        sq += rd(ws + CH_SQ  + b * 256 + t);
    }
    const float invn = 1.0f / (float)NTOT;
    float mean = su * invn;
    float var  = sq * invn - mean * mean;
    s_sh[t] = gamma[t] / sqrtf(var + 1e-5f);
    __syncthreads();

    // pair distances: pr = t>>4, each of 16 lanes handles 16 channels
    int pr = t >> 4, cl2 = t & 15;
    float pdl = 0.f, ndl = 0.f;
    #pragma unroll
    for (int k = 0; k < 16; ++k) {
        int cc = cl2 + 16 * k;
        float s = s_sh[cc];
        float* q = ws + TRI + (pr * 256 + cc) * 4;
        float q0 = rd(q + 0), q1 = rd(q + 1), q2 = rd(q + 2), q3 = rd(q + 3);
        pdl += s * s * q1 + 2e-6f * s * q0;
        ndl += s * s * q3 + 2e-6f * s * q2;
    }
    #pragma unroll
    for (int off = 8; off > 0; off >>= 1) {
        pdl += __shfl_down(pdl, off, 16);
        ndl += __shfl_down(ndl, off, 16);
    }
    if (cl2 == 0) {
        const float e2 = 1e-12f * (float)(CCH * NPIX);   // sum of eps^2 term
        tr[pr] = fmaxf(0.1f + sqrtf(pdl + e2) - sqrtf(ndl + e2), 0.0f);
    }

    // focal totals
    float l = 0.f, np = 0.f;
    if (t < 128) { l = rd(ws + FOC + 2 * t); np = rd(ws + FOC + 2 * t + 1); }
    block_reduce2_256(l, np);   // its __syncthreads also covers tr[] writes

    if (t == 0) {
        float trip = 0.f;
        #pragma unroll
        for (int p = 0; p < NPAIR; ++p) trip += tr[p];
        trip *= (1.0f / (float)NPAIR);
        out[0] = -l / fmaxf(np, 1.0f) + trip;
    }
}

extern "C" void kernel_launch(void* const* d_in, const int* in_sizes, int n_in,
                              void* d_out, int out_size, void* d_ws, size_t ws_size,
                              hipStream_t stream) {
    const float* simi  = (const float*)d_in[0];
    const float* hm    = (const float*)d_in[1];
    const float* hm_gt = (const float*)d_in[2];
    const int*   bboxf = (const int*)d_in[3];
    const int*   bboxm = (const int*)d_in[4];
    const float* gamma = (const float*)d_in[5];
    float* out = (float*)d_out;
    float* ws  = (float*)d_ws;

    hipMemsetAsync((unsigned int*)(ws + CNT), 0, sizeof(unsigned int), stream);
    mega<<<NBLOCKS, 256, 0, stream>>>(simi, hm, hm_gt, bboxf, bboxm, gamma, ws, out);
}

// Round 8
// 32.840 us; speedup vs baseline: 1.5569x; 1.5569x over previous
//
#include <hip/hip_runtime.h>
#include <math.h>

#define CCH 256
#define HMD 128
#define HW (HMD*HMD)          // 16384
#define NTOT (8*HW)           // 131072 per channel
#define OH 11
#define OW 8
#define NPIX (OH*OW)          // 88
#define NPAIR 16

// ws float layout (all slots written unconditionally each call -> no memset):
// [0..1023]       chan sum partial, slot pb = b*256+c (b in [0,4)), covers planes pb and pb+1024
// [1024..2047]    chan sumsq partial
// [2048..18431]   triplet partials: ((pair*256+c)*4) + {S1pd, S2pd, S1nd, S2nd}
// [18432..18687]  focal partials: 128 x {lsum, npos}
#define CH_SUM 0
#define CH_SQ  1024
#define TRI    2048
#define FOC    18432

#define NTRIP2   256     // 16 pairs x 16 channel-chunks
#define NFOCAL   128
#define NPLANE2  1024
#define NBLOCKS  (NTRIP2 + NFOCAL + NPLANE2)   // 1408 blocks, <=6 per CU, co-resident

__device__ __forceinline__ void block_reduce2_256(float& a, float& b) {
    #pragma unroll
    for (int off = 32; off > 0; off >>= 1) {
        a += __shfl_down(a, off, 64);
        b += __shfl_down(b, off, 64);
    }
    __shared__ float sa[4], sb[4];
    int wid  = threadIdx.x >> 6;
    int lane = threadIdx.x & 63;
    if (lane == 0) { sa[wid] = a; sb[wid] = b; }
    __syncthreads();
    if (threadIdx.x == 0) {
        a = sa[0] + sa[1] + sa[2] + sa[3];
        b = sb[0] + sb[1] + sb[2] + sb[3];
    }
}

// Single fused compute kernel, plain stores, no fences, no atomics.
// Roles: triplet [0,256), focal [256,384), planes [384,1408).
__global__ void mega(const float* __restrict__ simi,
                     const float* __restrict__ hm,
                     const float* __restrict__ gt,
                     const int* __restrict__ bboxf,
                     const int* __restrict__ bboxm,
                     float* __restrict__ ws) {
    const int bid = blockIdx.x;
    const int tid = threadIdx.x;

    if (bid < NTRIP2) {
        // ---- triplet gather: pair = bid>>4, channels chunk*16..+15 ----
        int pair  = bid >> 4;
        int chunk = bid & 15;

        __shared__ int   sYA[3][OH], sYB[3][OH], sXA[3][OW], sXB[3][OW];
        __shared__ float sWY[3][OH], sWX[3][OW];
        __shared__ int   sBase[3];

        if (tid < 3) {
            const int* bx;
            int bidx;
            if (tid == 0)      { bx = bboxf + pair * 4;        bidx = pair >> 2; }       // anchor
            else if (tid == 1) { bx = bboxf + (16 + pair) * 4; bidx = 4 + (pair >> 2); } // positive
            else               { bx = bboxm + pair * 4;        bidx = pair >> 1; }       // negative
            int x0 = bx[0], y0 = bx[1], x1 = bx[2], y1 = bx[3];
            float h = (float)(y1 - y0), w = (float)(x1 - x0);
            for (int j = 0; j < OH; ++j) {
                float sy = fminf(fmaxf((j + 0.5f) * h / (float)OH - 0.5f, 0.0f), h - 1.0f);
                int ylo = (int)floorf(sy);
                sYA[tid][j] = y0 + ylo;
                sYB[tid][j] = y0 + min(ylo + 1, y1 - y0 - 1);
                sWY[tid][j] = sy - (float)ylo;
            }
            for (int j = 0; j < OW; ++j) {
                float sx = fminf(fmaxf((j + 0.5f) * w / (float)OW - 0.5f, 0.0f), w - 1.0f);
                int xlo = (int)floorf(sx);
                sXA[tid][j] = x0 + xlo;
                sXB[tid][j] = x0 + min(xlo + 1, x1 - x0 - 1);
                sWX[tid][j] = sx - (float)xlo;
            }
            sBase[tid] = bidx * CCH * HW;
        }
        __syncthreads();

        // tid = cl*16 + x*2 + yh : cl in [0,16), x in [0,8), yh in {0,1}
        int cl = tid >> 4;
        int sub = tid & 15;
        int lx  = sub >> 1;
        int yh  = sub & 1;
        int c   = chunk * 16 + cl;

        const float* imgA = simi + sBase[0] + c * HW;
        const float* imgP = simi + sBase[1] + c * HW;
        const float* imgN = simi + sBase[2] + c * HW;

        float a1p = 0.f, a2p = 0.f, a1n = 0.f, a2n = 0.f;
        float wxA = sWX[0][lx], wxP = sWX[1][lx], wxN = sWX[2][lx];
        int xaA = sXA[0][lx], xbA = sXB[0][lx];
        int xaP = sXA[1][lx], xbP = sXB[1][lx];
        int xaN = sXA[2][lx], xbN = sXB[2][lx];

        #pragma unroll
        for (int yy = 0; yy < 6; ++yy) {
            int y = yh * 6 + yy;
            if (y < OH) {
                float wyA = sWY[0][y], wyP = sWY[1][y], wyN = sWY[2][y];
                int yaA = sYA[0][y] * HMD, ybA = sYB[0][y] * HMD;
                int yaP = sYA[1][y] * HMD, ybP = sYB[1][y] * HMD;
                int yaN = sYA[2][y] * HMD, ybN = sYB[2][y] * HMD;

                float vA, vP, vN;
                {
                    float v00 = imgA[yaA + xaA], v01 = imgA[yaA + xbA];
                    float v10 = imgA[ybA + xaA], v11 = imgA[ybA + xbA];
                    float top = (1.0f - wxA) * v00 + wxA * v01;
                    float bot = (1.0f - wxA) * v10 + wxA * v11;
                    vA = (1.0f - wyA) * top + wyA * bot;
                }
                {
                    float v00 = imgP[yaP + xaP], v01 = imgP[yaP + xbP];
                    float v10 = imgP[ybP + xaP], v11 = imgP[ybP + xbP];
                    float top = (1.0f - wxP) * v00 + wxP * v01;
                    float bot = (1.0f - wxP) * v10 + wxP * v11;
                    vP = (1.0f - wyP) * top + wyP * bot;
                }
                {
                    float v00 = imgN[yaN + xaN], v01 = imgN[yaN + xbN];
                    float v10 = imgN[ybN + xaN], v11 = imgN[ybN + xbN];
                    float top = (1.0f - wxN) * v00 + wxN * v01;
                    float bot = (1.0f - wxN) * v10 + wxN * v11;
                    vN = (1.0f - wyN) * top + wyN * bot;
                }
                float dp = vA - vP; a1p += dp; a2p += dp * dp;
                float dn = vA - vN; a1n += dn; a2n += dn * dn;
            }
        }
        // reduce across the 16 lanes sharing a channel (yh, then x)
        #pragma unroll
        for (int off = 1; off < 16; off <<= 1) {
            a1p += __shfl_down(a1p, off, 16);
            a2p += __shfl_down(a2p, off, 16);
            a1n += __shfl_down(a1n, off, 16);
            a2n += __shfl_down(a2n, off, 16);
        }
        if (sub == 0) {
            float* q = ws + TRI + (pair * 256 + c) * 4;
            q[0] = a1p; q[1] = a2p; q[2] = a1n; q[3] = a2n;
        }
    } else if (bid < NTRIP2 + NFOCAL) {
        // ---- focal partial ----
        int fb = bid - NTRIP2;
        int i = fb * 256 + tid;
        float4 hv = ((const float4*)hm)[i];
        float4 gv = ((const float4*)gt)[i];
        float lsum = 0.f, npos = 0.f;
        #pragma unroll
        for (int j = 0; j < 4; ++j) {
            float x = (&hv.x)[j], g = (&gv.x)[j];
            float pred = 1.0f / (1.0f + expf(-x));
            pred = fminf(fmaxf(pred, 1e-4f), 1.0f - 1e-4f);
            if (g == 1.0f) {
                float om = 1.0f - pred;
                lsum += logf(pred) * om * om;
                npos += 1.0f;
            } else {
                float gg = 1.0f - g;
                float g2 = gg * gg;
                lsum += logf(1.0f - pred) * pred * pred * (g2 * g2);
            }
        }
        block_reduce2_256(lsum, npos);
        if (tid == 0) { ws[FOC + 2 * fb] = lsum; ws[FOC + 2 * fb + 1] = npos; }
    } else {
        // ---- channel-plane sums: block handles planes pb and pb+1024 (same channel) ----
        int pb = bid - NTRIP2 - NFOCAL;           // 0..1023
        const float4* pa = (const float4*)(simi + (size_t)pb * HW);
        const float4* pc = (const float4*)(simi + (size_t)(pb + 1024) * HW);
        float s = 0.f, s2 = 0.f;
        #pragma unroll
        for (int it = 0; it < 16; ++it) {
            float4 va = pa[it * 256 + tid];
            float4 vb = pc[it * 256 + tid];
            s  += va.x + va.y + va.z + va.w;
            s2 += va.x*va.x + va.y*va.y + va.z*va.z + va.w*va.w;
            s  += vb.x + vb.y + vb.z + vb.w;
            s2 += vb.x*vb.x + vb.y*vb.y + vb.z*vb.z + vb.w*vb.w;
        }
        block_reduce2_256(s, s2);
        if (tid == 0) { ws[CH_SUM + pb] = s; ws[CH_SQ + pb] = s2; }
    }
}

// 1 block, 1024 threads (kernel boundary = free device-wide release/acquire).
// Wave w (t>>6) owns pair w for the triplet combine.
__global__ void finalize(const float* __restrict__ ws,
                         const float* __restrict__ gamma,
                         float* __restrict__ out) {
    __shared__ float s_sh[256], tr[NPAIR], fl[2][2];
    int t = threadIdx.x;

    if (t < 256) {
        float su = 0.f, sq = 0.f;
        #pragma unroll
        for (int b = 0; b < 4; ++b) {
            su += ws[CH_SUM + b * 256 + t];
            sq += ws[CH_SQ  + b * 256 + t];
        }
        const float invn = 1.0f / (float)NTOT;
        float mean = su * invn;
        float var  = sq * invn - mean * mean;
        s_sh[t] = gamma[t] / sqrtf(var + 1e-5f);
    }
    __syncthreads();

    // triplet combine: wave = pair (16 waves), lane handles channels lane, lane+64, ...
    int pr = t >> 6, lane = t & 63;
    float pdl = 0.f, ndl = 0.f;
    #pragma unroll
    for (int k = 0; k < 4; ++k) {
        int c = lane + 64 * k;
        float s = s_sh[c];
        const float* q = ws + TRI + (pr * 256 + c) * 4;
        pdl += s * s * q[1] + 2e-6f * s * q[0];
        ndl += s * s * q[3] + 2e-6f * s * q[2];
    }
    #pragma unroll
    for (int off = 32; off > 0; off >>= 1) {
        pdl += __shfl_down(pdl, off, 64);
        ndl += __shfl_down(ndl, off, 64);
    }
    if (lane == 0) {
        const float e2 = 1e-12f * (float)(CCH * NPIX);   // sum of eps^2 term
        tr[pr] = fmaxf(0.1f + sqrtf(pdl + e2) - sqrtf(ndl + e2), 0.0f);
    }

    // focal totals: threads 0..127 read the 128 partial pairs (waves 0 and 1)
    float l = 0.f, np = 0.f;
    if (t < 128) { l = ws[FOC + 2 * t]; np = ws[FOC + 2 * t + 1]; }
    if (t < 128) {
        #pragma unroll
        for (int off = 32; off > 0; off >>= 1) {
            l  += __shfl_down(l, off, 64);
            np += __shfl_down(np, off, 64);
        }
        if ((t & 63) == 0) { fl[t >> 6][0] = l; fl[t >> 6][1] = np; }
    }
    __syncthreads();

    if (t == 0) {
        float trip = 0.f;
        #pragma unroll
        for (int p = 0; p < NPAIR; ++p) trip += tr[p];
        trip *= (1.0f / (float)NPAIR);
        float lt  = fl[0][0] + fl[1][0];
        float npt = fl[0][1] + fl[1][1];
        out[0] = -lt / fmaxf(npt, 1.0f) + trip;
    }
}

extern "C" void kernel_launch(void* const* d_in, const int* in_sizes, int n_in,
                              void* d_out, int out_size, void* d_ws, size_t ws_size,
                              hipStream_t stream) {
    const float* simi  = (const float*)d_in[0];
    const float* hm    = (const float*)d_in[1];
    const float* hm_gt = (const float*)d_in[2];
    const int*   bboxf = (const int*)d_in[3];
    const int*   bboxm = (const int*)d_in[4];
    const float* gamma = (const float*)d_in[5];
    float* out = (float*)d_out;
    float* ws  = (float*)d_ws;

    mega<<<NBLOCKS, 256, 0, stream>>>(simi, hm, hm_gt, bboxf, bboxm, ws);
    finalize<<<1, 1024, 0, stream>>>(ws, gamma, out);
}

// Round 9
// 32.127 us; speedup vs baseline: 1.5915x; 1.0222x over previous
//
#include <hip/hip_runtime.h>
#include <math.h>

#define CCH 256
#define HMD 128
#define HW (HMD*HMD)          // 16384
#define NTOT (8*HW)           // 131072 per channel
#define OH 11
#define OW 8
#define NPIX (OH*OW)          // 88
#define NPAIR 16

// ws float layout (all slots written unconditionally each call -> no memset):
// [0..1023]       chan sum partial, slot pb = b*256+c (b in [0,4)), covers planes pb and pb+1024
// [1024..2047]    chan sumsq partial
// [2048..18431]   triplet partials: ((pair*256+c)*4) + {S1pd, S2pd, S1nd, S2nd}
// [18432..18687]  focal partials: 128 x {lsum, npos}
#define CH_SUM 0
#define CH_SQ  1024
#define TRI    2048
#define FOC    18432

#define NTRIP3   512     // 16 pairs x 32 channel-chunks (8 channels each)
#define NFOCAL   128
#define NPLANE2  1024
#define NBLOCKS  (NTRIP3 + NFOCAL + NPLANE2)   // 1664 blocks, co-resident (<=7/CU)

__device__ __forceinline__ void block_reduce2_256(float& a, float& b) {
    #pragma unroll
    for (int off = 32; off > 0; off >>= 1) {
        a += __shfl_down(a, off, 64);
        b += __shfl_down(b, off, 64);
    }
    __shared__ float sa[4], sb[4];
    int wid  = threadIdx.x >> 6;
    int lane = threadIdx.x & 63;
    if (lane == 0) { sa[wid] = a; sb[wid] = b; }
    __syncthreads();
    if (threadIdx.x == 0) {
        a = sa[0] + sa[1] + sa[2] + sa[3];
        b = sb[0] + sb[1] + sb[2] + sb[3];
    }
}

// Single fused compute kernel, plain stores, no fences, no atomics.
// Roles: triplet [0,512), focal [512,640), planes [640,1664).
__global__ void mega(const float* __restrict__ simi,
                     const float* __restrict__ hm,
                     const float* __restrict__ gt,
                     const int* __restrict__ bboxf,
                     const int* __restrict__ bboxm,
                     float* __restrict__ ws) {
    const int bid = blockIdx.x;
    const int tid = threadIdx.x;

    if (bid < NTRIP3) {
        // ---- triplet gather: pair = bid>>5, channels chunk*8..+7 ----
        int pair  = bid >> 5;
        int chunk = bid & 31;

        __shared__ int   sYA[3][OH], sYB[3][OH], sXA[3][OW], sXB[3][OW];
        __shared__ float sWY[3][OH], sWX[3][OW];
        __shared__ int   sBase[3];

        if (tid < 3) {
            const int* bx;
            int bidx;
            if (tid == 0)      { bx = bboxf + pair * 4;        bidx = pair >> 2; }       // anchor
            else if (tid == 1) { bx = bboxf + (16 + pair) * 4; bidx = 4 + (pair >> 2); } // positive
            else               { bx = bboxm + pair * 4;        bidx = pair >> 1; }       // negative
            int x0 = bx[0], y0 = bx[1], x1 = bx[2], y1 = bx[3];
            float h = (float)(y1 - y0), w = (float)(x1 - x0);
            for (int j = 0; j < OH; ++j) {
                float sy = fminf(fmaxf((j + 0.5f) * h / (float)OH - 0.5f, 0.0f), h - 1.0f);
                int ylo = (int)floorf(sy);
                sYA[tid][j] = y0 + ylo;
                sYB[tid][j] = y0 + min(ylo + 1, y1 - y0 - 1);
                sWY[tid][j] = sy - (float)ylo;
            }
            for (int j = 0; j < OW; ++j) {
                float sx = fminf(fmaxf((j + 0.5f) * w / (float)OW - 0.5f, 0.0f), w - 1.0f);
                int xlo = (int)floorf(sx);
                sXA[tid][j] = x0 + xlo;
                sXB[tid][j] = x0 + min(xlo + 1, x1 - x0 - 1);
                sWX[tid][j] = sx - (float)xlo;
            }
            sBase[tid] = bidx * CCH * HW;
        }
        __syncthreads();

        // tid = cl*32 + lx*4 + yq : cl in [0,8), lx in [0,8), yq in [0,4)
        int cl  = tid >> 5;
        int sub = tid & 31;
        int lx  = sub >> 2;
        int yq  = sub & 3;
        int c   = chunk * 8 + cl;

        const float* imgA = simi + sBase[0] + c * HW;
        const float* imgP = simi + sBase[1] + c * HW;
        const float* imgN = simi + sBase[2] + c * HW;

        float a1p = 0.f, a2p = 0.f, a1n = 0.f, a2n = 0.f;
        float wxA = sWX[0][lx], wxP = sWX[1][lx], wxN = sWX[2][lx];
        int xaA = sXA[0][lx], xbA = sXB[0][lx];
        int xaP = sXA[1][lx], xbP = sXB[1][lx];
        int xaN = sXA[2][lx], xbN = sXB[2][lx];

        #pragma unroll
        for (int yy = 0; yy < 3; ++yy) {
            int y = yq * 3 + yy;
            if (y < OH) {
                float wyA = sWY[0][y], wyP = sWY[1][y], wyN = sWY[2][y];
                int yaA = sYA[0][y] * HMD, ybA = sYB[0][y] * HMD;
                int yaP = sYA[1][y] * HMD, ybP = sYB[1][y] * HMD;
                int yaN = sYA[2][y] * HMD, ybN = sYB[2][y] * HMD;

                float vA, vP, vN;
                {
                    float v00 = imgA[yaA + xaA], v01 = imgA[yaA + xbA];
                    float v10 = imgA[ybA + xaA], v11 = imgA[ybA + xbA];
                    float top = (1.0f - wxA) * v00 + wxA * v01;
                    float bot = (1.0f - wxA) * v10 + wxA * v11;
                    vA = (1.0f - wyA) * top + wyA * bot;
                }
                {
                    float v00 = imgP[yaP + xaP], v01 = imgP[yaP + xbP];
                    float v10 = imgP[ybP + xaP], v11 = imgP[ybP + xbP];
                    float top = (1.0f - wxP) * v00 + wxP * v01;
                    float bot = (1.0f - wxP) * v10 + wxP * v11;
                    vP = (1.0f - wyP) * top + wyP * bot;
                }
                {
                    float v00 = imgN[yaN + xaN], v01 = imgN[yaN + xbN];
                    float v10 = imgN[ybN + xaN], v11 = imgN[ybN + xbN];
                    float top = (1.0f - wxN) * v00 + wxN * v01;
                    float bot = (1.0f - wxN) * v10 + wxN * v11;
                    vN = (1.0f - wyN) * top + wyN * bot;
                }
                float dp = vA - vP; a1p += dp; a2p += dp * dp;
                float dn = vA - vN; a1n += dn; a2n += dn * dn;
            }
        }
        // reduce across the 32 lanes sharing a channel
        #pragma unroll
        for (int off = 1; off < 32; off <<= 1) {
            a1p += __shfl_down(a1p, off, 32);
            a2p += __shfl_down(a2p, off, 32);
            a1n += __shfl_down(a1n, off, 32);
            a2n += __shfl_down(a2n, off, 32);
        }
        if (sub == 0) {
            float* q = ws + TRI + (pair * 256 + c) * 4;
            q[0] = a1p; q[1] = a2p; q[2] = a1n; q[3] = a2n;
        }
    } else if (bid < NTRIP3 + NFOCAL) {
        // ---- focal partial ----
        int fb = bid - NTRIP3;
        int i = fb * 256 + tid;
        float4 hv = ((const float4*)hm)[i];
        float4 gv = ((const float4*)gt)[i];
        float lsum = 0.f, npos = 0.f;
        #pragma unroll
        for (int j = 0; j < 4; ++j) {
            float x = (&hv.x)[j], g = (&gv.x)[j];
            float pred = 1.0f / (1.0f + expf(-x));
            pred = fminf(fmaxf(pred, 1e-4f), 1.0f - 1e-4f);
            if (g == 1.0f) {
                float om = 1.0f - pred;
                lsum += logf(pred) * om * om;
                npos += 1.0f;
            } else {
                float gg = 1.0f - g;
                float g2 = gg * gg;
                lsum += logf(1.0f - pred) * pred * pred * (g2 * g2);
            }
        }
        block_reduce2_256(lsum, npos);
        if (tid == 0) { ws[FOC + 2 * fb] = lsum; ws[FOC + 2 * fb + 1] = npos; }
    } else {
        // ---- channel-plane sums: block handles planes pb and pb+1024 (same channel) ----
        int pb = bid - NTRIP3 - NFOCAL;           // 0..1023
        const float4* pa = (const float4*)(simi + (size_t)pb * HW);
        const float4* pc = (const float4*)(simi + (size_t)(pb + 1024) * HW);
        float s = 0.f, s2 = 0.f;
        #pragma unroll
        for (int it = 0; it < 16; ++it) {
            float4 va = pa[it * 256 + tid];
            float4 vb = pc[it * 256 + tid];
            s  += va.x + va.y + va.z + va.w;
            s2 += va.x*va.x + va.y*va.y + va.z*va.z + va.w*va.w;
            s  += vb.x + vb.y + vb.z + vb.w;
            s2 += vb.x*vb.x + vb.y*vb.y + vb.z*vb.z + vb.w*vb.w;
        }
        block_reduce2_256(s, s2);
        if (tid == 0) { ws[CH_SUM + pb] = s; ws[CH_SQ + pb] = s2; }
    }
}

// 1 block, 1024 threads (kernel boundary = free device-wide release/acquire).
// Wave w (t>>6) owns pair w for the triplet combine.
__global__ void finalize(const float* __restrict__ ws,
                         const float* __restrict__ gamma,
                         float* __restrict__ out) {
    __shared__ float s_sh[256], tr[NPAIR], fl[2][2];
    int t = threadIdx.x;

    if (t < 256) {
        float su = 0.f, sq = 0.f;
        #pragma unroll
        for (int b = 0; b < 4; ++b) {
            su += ws[CH_SUM + b * 256 + t];
            sq += ws[CH_SQ  + b * 256 + t];
        }
        const float invn = 1.0f / (float)NTOT;
        float mean = su * invn;
        float var  = sq * invn - mean * mean;
        s_sh[t] = gamma[t] / sqrtf(var + 1e-5f);
    }
    __syncthreads();

    // triplet combine: wave = pair (16 waves), lane handles channels lane, lane+64, ...
    int pr = t >> 6, lane = t & 63;
    float pdl = 0.f, ndl = 0.f;
    #pragma unroll
    for (int k = 0; k < 4; ++k) {
        int c = lane + 64 * k;
        float s = s_sh[c];
        const float* q = ws + TRI + (pr * 256 + c) * 4;
        pdl += s * s * q[1] + 2e-6f * s * q[0];
        ndl += s * s * q[3] + 2e-6f * s * q[2];
    }
    #pragma unroll
    for (int off = 32; off > 0; off >>= 1) {
        pdl += __shfl_down(pdl, off, 64);
        ndl += __shfl_down(ndl, off, 64);
    }
    if (lane == 0) {
        const float e2 = 1e-12f * (float)(CCH * NPIX);   // sum of eps^2 term
        tr[pr] = fmaxf(0.1f + sqrtf(pdl + e2) - sqrtf(ndl + e2), 0.0f);
    }

    // focal totals: threads 0..127 read the 128 partial pairs (waves 0 and 1)
    float l = 0.f, np = 0.f;
    if (t < 128) { l = ws[FOC + 2 * t]; np = ws[FOC + 2 * t + 1]; }
    if (t < 128) {
        #pragma unroll
        for (int off = 32; off > 0; off >>= 1) {
            l  += __shfl_down(l, off, 64);
            np += __shfl_down(np, off, 64);
        }
        if ((t & 63) == 0) { fl[t >> 6][0] = l; fl[t >> 6][1] = np; }
    }
    __syncthreads();

    if (t == 0) {
        float trip = 0.f;
        #pragma unroll
        for (int p = 0; p < NPAIR; ++p) trip += tr[p];
        trip *= (1.0f / (float)NPAIR);
        float lt  = fl[0][0] + fl[1][0];
        float npt = fl[0][1] + fl[1][1];
        out[0] = -lt / fmaxf(npt, 1.0f) + trip;
    }
}

extern "C" void kernel_launch(void* const* d_in, const int* in_sizes, int n_in,
                              void* d_out, int out_size, void* d_ws, size_t ws_size,
                              hipStream_t stream) {
    const float* simi  = (const float*)d_in[0];
    const float* hm    = (const float*)d_in[1];
    const float* hm_gt = (const float*)d_in[2];
    const int*   bboxf = (const int*)d_in[3];
    const int*   bboxm = (const int*)d_in[4];
    const float* gamma = (const float*)d_in[5];
    float* out = (float*)d_out;
    float* ws  = (float*)d_ws;

    mega<<<NBLOCKS, 256, 0, stream>>>(simi, hm, hm_gt, bboxf, bboxm, ws);
    finalize<<<1, 1024, 0, stream>>>(ws, gamma, out);
}

// Round 10
// 31.880 us; speedup vs baseline: 1.6038x; 1.0077x over previous
//
#include <hip/hip_runtime.h>
#include <math.h>

#define CCH 256
#define HMD 128
#define HW (HMD*HMD)          // 16384
#define NTOT (8*HW)           // 131072 per channel
#define OH 11
#define OW 8
#define NPIX (OH*OW)          // 88
#define NPAIR 16

// ws float layout (all slots written unconditionally each call -> no memset):
// [0..1023]       chan sum partial, slot pb = b*256+c (b in [0,4)), covers planes pb and pb+1024
// [1024..2047]    chan sumsq partial
// [2048..18431]   triplet partials: ((pair*256+c)*4) + {S1pd, S2pd, S1nd, S2nd}
// [18432..18687]  focal partials: 128 x {lsum, npos}
#define CH_SUM 0
#define CH_SQ  1024
#define TRI    2048
#define FOC    18432

#define NTRIP3   512     // 16 pairs x 32 channel-chunks (8 channels each)
#define NFOCAL   128
#define NPLANE2  1024
#define NBLOCKS  (NTRIP3 + NFOCAL + NPLANE2)   // 1664 blocks, co-resident (<=7/CU)

__device__ __forceinline__ void block_reduce2_256(float& a, float& b) {
    #pragma unroll
    for (int off = 32; off > 0; off >>= 1) {
        a += __shfl_down(a, off, 64);
        b += __shfl_down(b, off, 64);
    }
    __shared__ float sa[4], sb[4];
    int wid  = threadIdx.x >> 6;
    int lane = threadIdx.x & 63;
    if (lane == 0) { sa[wid] = a; sb[wid] = b; }
    __syncthreads();
    if (threadIdx.x == 0) {
        a = sa[0] + sa[1] + sa[2] + sa[3];
        b = sb[0] + sb[1] + sb[2] + sb[3];
    }
}

// Single fused compute kernel, plain stores, no fences, no atomics.
// Roles: triplet [0,512), focal [512,640), planes [640,1664).
__global__ void mega(const float* __restrict__ simi,
                     const float* __restrict__ hm,
                     const float* __restrict__ gt,
                     const int* __restrict__ bboxf,
                     const int* __restrict__ bboxm,
                     float* __restrict__ ws) {
    const int bid = blockIdx.x;
    const int tid = threadIdx.x;

    if (bid < NTRIP3) {
        // ---- triplet gather: pair = bid>>5, channels chunk*8..+7 ----
        int pair  = bid >> 5;
        int chunk = bid & 31;

        __shared__ int   sYA[3][OH], sYB[3][OH], sXA[3][OW];
        __shared__ float sWY[3][OH], sWX[3][OW];
        __shared__ int   sBase[3];

        if (tid < 3) {
            const int* bx;
            int bidx;
            if (tid == 0)      { bx = bboxf + pair * 4;        bidx = pair >> 2; }       // anchor
            else if (tid == 1) { bx = bboxf + (16 + pair) * 4; bidx = 4 + (pair >> 2); } // positive
            else               { bx = bboxm + pair * 4;        bidx = pair >> 1; }       // negative
            int x0 = bx[0], y0 = bx[1], x1 = bx[2], y1 = bx[3];
            float h = (float)(y1 - y0), w = (float)(x1 - x0);
            for (int j = 0; j < OH; ++j) {
                float sy = fminf(fmaxf((j + 0.5f) * h / (float)OH - 0.5f, 0.0f), h - 1.0f);
                int ylo = (int)floorf(sy);
                sYA[tid][j] = y0 + ylo;
                sYB[tid][j] = y0 + min(ylo + 1, y1 - y0 - 1);
                sWY[tid][j] = sy - (float)ylo;
            }
            for (int j = 0; j < OW; ++j) {
                float sx = fminf(fmaxf((j + 0.5f) * w / (float)OW - 0.5f, 0.0f), w - 1.0f);
                int xlo = (int)floorf(sx);
                // NOTE: when xlo+1 > w-1 the reference clamps xhi to xlo, but then
                // wx = sx - xlo = 0 exactly, so the v01/v11 taps have zero weight.
                // Since xa <= 126 always (xlo <= w-1-? see analysis: xlo <= w-1, x0+w-1 <= x1-1 <= 126),
                // an 8-byte load [xa, xa+1] is always in-bounds and the second lane is a don't-care
                // in the clamped case. So we drop sXB entirely and load float2 pairs.
                sXA[tid][j] = x0 + xlo;
                sWX[tid][j] = sx - (float)xlo;
            }
            sBase[tid] = bidx * CCH * HW;
        }
        __syncthreads();

        // tid = cl*32 + lx*4 + yq : cl in [0,8), lx in [0,8), yq in [0,4)
        int cl  = tid >> 5;
        int sub = tid & 31;
        int lx  = sub >> 2;
        int yq  = sub & 3;
        int c   = chunk * 8 + cl;

        const float* imgA = simi + sBase[0] + c * HW;
        const float* imgP = simi + sBase[1] + c * HW;
        const float* imgN = simi + sBase[2] + c * HW;

        float a1p = 0.f, a2p = 0.f, a1n = 0.f, a2n = 0.f;
        float wxA = sWX[0][lx], wxP = sWX[1][lx], wxN = sWX[2][lx];
        int xaA = sXA[0][lx];
        int xaP = sXA[1][lx];
        int xaN = sXA[2][lx];

        #pragma unroll
        for (int yy = 0; yy < 3; ++yy) {
            int y = yq * 3 + yy;
            if (y < OH) {
                float wyA = sWY[0][y], wyP = sWY[1][y], wyN = sWY[2][y];
                int yaA = sYA[0][y] * HMD, ybA = sYB[0][y] * HMD;
                int yaP = sYA[1][y] * HMD, ybP = sYB[1][y] * HMD;
                int yaN = sYA[2][y] * HMD, ybN = sYB[2][y] * HMD;

                float vA, vP, vN;
                {
                    float2 t0 = *(const float2*)(imgA + yaA + xaA);
                    float2 t1 = *(const float2*)(imgA + ybA + xaA);
                    float top = (1.0f - wxA) * t0.x + wxA * t0.y;
                    float bot = (1.0f - wxA) * t1.x + wxA * t1.y;
                    vA = (1.0f - wyA) * top + wyA * bot;
                }
                {
                    float2 t0 = *(const float2*)(imgP + yaP + xaP);
                    float2 t1 = *(const float2*)(imgP + ybP + xaP);
                    float top = (1.0f - wxP) * t0.x + wxP * t0.y;
                    float bot = (1.0f - wxP) * t1.x + wxP * t1.y;
                    vP = (1.0f - wyP) * top + wyP * bot;
                }
                {
                    float2 t0 = *(const float2*)(imgN + yaN + xaN);
                    float2 t1 = *(const float2*)(imgN + ybN + xaN);
                    float top = (1.0f - wxN) * t0.x + wxN * t0.y;
                    float bot = (1.0f - wxN) * t1.x + wxN * t1.y;
                    vN = (1.0f - wyN) * top + wyN * bot;
                }
                float dp = vA - vP; a1p += dp; a2p += dp * dp;
                float dn = vA - vN; a1n += dn; a2n += dn * dn;
            }
        }
        // reduce across the 32 lanes sharing a channel
        #pragma unroll
        for (int off = 1; off < 32; off <<= 1) {
            a1p += __shfl_down(a1p, off, 32);
            a2p += __shfl_down(a2p, off, 32);
            a1n += __shfl_down(a1n, off, 32);
            a2n += __shfl_down(a2n, off, 32);
        }
        if (sub == 0) {
            float* q = ws + TRI + (pair * 256 + c) * 4;
            q[0] = a1p; q[1] = a2p; q[2] = a1n; q[3] = a2n;
        }
    } else if (bid < NTRIP3 + NFOCAL) {
        // ---- focal partial ----
        int fb = bid - NTRIP3;
        int i = fb * 256 + tid;
        float4 hv = ((const float4*)hm)[i];
        float4 gv = ((const float4*)gt)[i];
        float lsum = 0.f, npos = 0.f;
        #pragma unroll
        for (int j = 0; j < 4; ++j) {
            float x = (&hv.x)[j], g = (&gv.x)[j];
            float pred = 1.0f / (1.0f + expf(-x));
            pred = fminf(fmaxf(pred, 1e-4f), 1.0f - 1e-4f);
            if (g == 1.0f) {
                float om = 1.0f - pred;
                lsum += logf(pred) * om * om;
                npos += 1.0f;
            } else {
                float gg = 1.0f - g;
                float g2 = gg * gg;
                lsum += logf(1.0f - pred) * pred * pred * (g2 * g2);
            }
        }
        block_reduce2_256(lsum, npos);
        if (tid == 0) { ws[FOC + 2 * fb] = lsum; ws[FOC + 2 * fb + 1] = npos; }
    } else {
        // ---- channel-plane sums: block handles planes pb and pb+1024 (same channel) ----
        int pb = bid - NTRIP3 - NFOCAL;           // 0..1023
        const float4* pa = (const float4*)(simi + (size_t)pb * HW);
        const float4* pc = (const float4*)(simi + (size_t)(pb + 1024) * HW);
        float s = 0.f, s2 = 0.f;
        #pragma unroll
        for (int it = 0; it < 16; ++it) {
            float4 va = pa[it * 256 + tid];
            float4 vb = pc[it * 256 + tid];
            s  += va.x + va.y + va.z + va.w;
            s2 += va.x*va.x + va.y*va.y + va.z*va.z + va.w*va.w;
            s  += vb.x + vb.y + vb.z + vb.w;
            s2 += vb.x*vb.x + vb.y*vb.y + vb.z*vb.z + vb.w*vb.w;
        }
        block_reduce2_256(s, s2);
        if (tid == 0) { ws[CH_SUM + pb] = s; ws[CH_SQ + pb] = s2; }
    }
}

// 1 block, 1024 threads (kernel boundary = free device-wide release/acquire).
// Wave w (t>>6) owns pair w for the triplet combine.
__global__ void finalize(const float* __restrict__ ws,
                         const float* __restrict__ gamma,
                         float* __restrict__ out) {
    __shared__ float s_sh[256], tr[NPAIR], fl[2][2];
    int t = threadIdx.x;

    if (t < 256) {
        float su = 0.f, sq = 0.f;
        #pragma unroll
        for (int b = 0; b < 4; ++b) {
            su += ws[CH_SUM + b * 256 + t];
            sq += ws[CH_SQ  + b * 256 + t];
        }
        const float invn = 1.0f / (float)NTOT;
        float mean = su * invn;
        float var  = sq * invn - mean * mean;
        s_sh[t] = gamma[t] / sqrtf(var + 1e-5f);
    }
    __syncthreads();

    // triplet combine: wave = pair (16 waves), lane handles channels lane, lane+64, ...
    int pr = t >> 6, lane = t & 63;
    float pdl = 0.f, ndl = 0.f;
    #pragma unroll
    for (int k = 0; k < 4; ++k) {
        int c = lane + 64 * k;
        float s = s_sh[c];
        const float* q = ws + TRI + (pr * 256 + c) * 4;
        pdl += s * s * q[1] + 2e-6f * s * q[0];
        ndl += s * s * q[3] + 2e-6f * s * q[2];
    }
    #pragma unroll
    for (int off = 32; off > 0; off >>= 1) {
        pdl += __shfl_down(pdl, off, 64);
        ndl += __shfl_down(ndl, off, 64);
    }
    if (lane == 0) {
        const float e2 = 1e-12f * (float)(CCH * NPIX);   // sum of eps^2 term
        tr[pr] = fmaxf(0.1f + sqrtf(pdl + e2) - sqrtf(ndl + e2), 0.0f);
    }

    // focal totals: threads 0..127 read the 128 partial pairs (waves 0 and 1)
    float l = 0.f, np = 0.f;
    if (t < 128) { l = ws[FOC + 2 * t]; np = ws[FOC + 2 * t + 1]; }
    if (t < 128) {
        #pragma unroll
        for (int off = 32; off > 0; off >>= 1) {
            l  += __shfl_down(l, off, 64);
            np += __shfl_down(np, off, 64);
        }
        if ((t & 63) == 0) { fl[t >> 6][0] = l; fl[t >> 6][1] = np; }
    }
    __syncthreads();

    if (t == 0) {
        float trip = 0.f;
        #pragma unroll
        for (int p = 0; p < NPAIR; ++p) trip += tr[p];
        trip *= (1.0f / (float)NPAIR);
        float lt  = fl[0][0] + fl[1][0];
        float npt = fl[0][1] + fl[1][1];
        out[0] = -lt / fmaxf(npt, 1.0f) + trip;
    }
}

extern "C" void kernel_launch(void* const* d_in, const int* in_sizes, int n_in,
                              void* d_out, int out_size, void* d_ws, size_t ws_size,
                              hipStream_t stream) {
    const float* simi  = (const float*)d_in[0];
    const float* hm    = (const float*)d_in[1];
    const float* hm_gt = (const float*)d_in[2];
    const int*   bboxf = (const int*)d_in[3];
    const int*   bboxm = (const int*)d_in[4];
    const float* gamma = (const float*)d_in[5];
    float* out = (float*)d_out;
    float* ws  = (float*)d_ws;

    mega<<<NBLOCKS, 256, 0, stream>>>(simi, hm, hm_gt, bboxf, bboxm, ws);
    finalize<<<1, 1024, 0, stream>>>(ws, gamma, out);
}